// Round 1
// baseline (15960.164 us; speedup 1.0000x reference)
//
#include <hip/hip_runtime.h>
#include <hip/hip_bf16.h>

// ---------------- constants ----------------
static constexpr int T_  = 512;
static constexpr int B_  = 64;
static constexpr int I_  = 128;
static constexpr int H_  = 2048;   // fc1 out
static constexpr int H1_ = 1024;   // lstm1 hidden
static constexpr int F2_ = 512;    // fc2 out
static constexpr int H2_ = 256;    // lstm2 hidden
static constexpr int O_  = 64;     // output
static constexpr int G1N = 4096;   // 4*H1
static constexpr int G2N = 1024;   // 4*H2

typedef __attribute__((ext_vector_type(8))) __bf16 bfx8;
typedef __attribute__((ext_vector_type(4))) __bf16 bfx4;
typedef __attribute__((ext_vector_type(4))) float  fx4;

#define DEV __device__ __forceinline__

DEV fx4 mfma16(bfx8 a, bfx8 b, fx4 c) {
  return __builtin_amdgcn_mfma_f32_16x16x32_bf16(a, b, c, 0, 0, 0);
}
DEV float sigmoidf_(float x) { return 1.0f / (1.0f + __expf(-x)); }
DEV float leaky_tanh_(float x) { return tanhf(x * (2.0f / 3.0f)) * 1.7159f + x * 0.01f; }

// ---------------- fp32 -> bf16 conversion ----------------
__global__ void k_f2b(const float* __restrict__ s, __bf16* __restrict__ d, int n4) {
  int i = blockIdx.x * blockDim.x + threadIdx.x;
  int st = gridDim.x * blockDim.x;
  for (; i < n4; i += st) {
    float4 v = ((const float4*)s)[i];
    bfx4 o = { (__bf16)v.x, (__bf16)v.y, (__bf16)v.z, (__bf16)v.w };
    ((bfx4*)d)[i] = o;
  }
}

// ---------------- big GEMM: C[M,N] = A[M,K](bf16) @ W[N,K](bf16)^T ----------------
// epi==0: write fp32 to outF.  epi==1: write bf16 leaky_tanh(x + bias[col]) to outB.
__launch_bounds__(256)
__global__ void k_gemm(const __bf16* __restrict__ A, const __bf16* __restrict__ W,
                       float* __restrict__ outF, __bf16* __restrict__ outB,
                       const float* __restrict__ bias,
                       int M, int N, int K, int epi)
{
  __shared__ __bf16 As[128][32];
  __shared__ __bf16 Ws[128][32];
  const int tid = threadIdx.x;
  const int lane = tid & 63;
  const int wave = tid >> 6;
  const int wm = wave >> 1, wn = wave & 1;
  const int m0 = blockIdx.y * 128, n0 = blockIdx.x * 128;
  const int r1 = tid >> 2, c1v = (tid & 3) * 8;
  const int kr = (lane >> 4) * 8, rr = lane & 15;
  fx4 acc[4][4] = {};
  for (int k0 = 0; k0 < K; k0 += 32) {
    __syncthreads();
    *(bfx8*)&As[r1][c1v]      = *(const bfx8*)&A[(size_t)(m0 + r1) * K + k0 + c1v];
    *(bfx8*)&As[r1 + 64][c1v] = *(const bfx8*)&A[(size_t)(m0 + r1 + 64) * K + k0 + c1v];
    *(bfx8*)&Ws[r1][c1v]      = *(const bfx8*)&W[(size_t)(n0 + r1) * K + k0 + c1v];
    *(bfx8*)&Ws[r1 + 64][c1v] = *(const bfx8*)&W[(size_t)(n0 + r1 + 64) * K + k0 + c1v];
    __syncthreads();
    bfx8 a[4], b[4];
#pragma unroll
    for (int mi = 0; mi < 4; ++mi) a[mi] = *(const bfx8*)&As[wm*64 + mi*16 + rr][kr];
#pragma unroll
    for (int ni = 0; ni < 4; ++ni) b[ni] = *(const bfx8*)&Ws[wn*64 + ni*16 + rr][kr];
#pragma unroll
    for (int mi = 0; mi < 4; ++mi)
#pragma unroll
      for (int ni = 0; ni < 4; ++ni)
        acc[mi][ni] = mfma16(a[mi], b[ni], acc[mi][ni]);
  }
  const int cr = (lane >> 4) * 4, cc = lane & 15;
#pragma unroll
  for (int mi = 0; mi < 4; ++mi)
#pragma unroll
    for (int ni = 0; ni < 4; ++ni) {
      int col = n0 + wn*64 + ni*16 + cc;
#pragma unroll
      for (int r = 0; r < 4; ++r) {
        int row = m0 + wm*64 + mi*16 + cr + r;
        float v = acc[mi][ni][r];
        if (epi) {
          outB[(size_t)row * N + col] = (__bf16)leaky_tanh_(v + bias[col]);
        } else {
          outF[(size_t)row * N + col] = v;
        }
      }
    }
}

// ---------------- shared small-GEMM helper ----------------
// acc[4] += A[64 x K] @ W[64 rows x K]^T restricted to this wave's 16 cols (wave*16..+16)
DEV void gemm_bk64(const __bf16* __restrict__ A, int lda,
                   const __bf16* __restrict__ W, int ldw, int K,
                   __bf16 (*As)[64], __bf16 (*Ws)[64], fx4* acc)
{
  const int tid = threadIdx.x, lane = tid & 63, wave = tid >> 6;
  const int kr = (lane >> 4) * 8, rr = lane & 15;
  for (int k0 = 0; k0 < K; k0 += 64) {
    __syncthreads();
#pragma unroll
    for (int i = 0; i < 2; ++i) {
      int s = tid + i * 256;
      int r = s >> 3, c = (s & 7) * 8;
      *(bfx8*)&As[r][c] = *(const bfx8*)&A[(size_t)r * lda + k0 + c];
      *(bfx8*)&Ws[r][c] = *(const bfx8*)&W[(size_t)r * ldw + k0 + c];
    }
    __syncthreads();
#pragma unroll
    for (int kh = 0; kh < 2; ++kh) {
      bfx8 b = *(const bfx8*)&Ws[wave*16 + rr][kh*32 + kr];
#pragma unroll
      for (int mi = 0; mi < 4; ++mi) {
        bfx8 a = *(const bfx8*)&As[mi*16 + rr][kh*32 + kr];
        acc[mi] = mfma16(a, b, acc[mi]);
      }
    }
  }
}

// ---------------- fused step kernel F: [blocks 0..63] LSTM1(t)  |  [64..71] LSTM2(t-1) ----
__launch_bounds__(256)
__global__ void k_F(int do_l1, int do_l2,
                    const float* __restrict__ G1c, int tc,
                    const __bf16* __restrict__ h1p, __bf16* __restrict__ h1n,
                    float* __restrict__ c1,
                    const __bf16* __restrict__ whh1,
                    const float* __restrict__ bih1, const float* __restrict__ bhh1,
                    const __bf16* __restrict__ x2, const __bf16* __restrict__ wih2,
                    const float* __restrict__ g2p, float* __restrict__ c2,
                    __bf16* __restrict__ h2)
{
  __shared__ __align__(16) char smem[57344];
  const int tid = threadIdx.x, lane = tid & 63, wave = tid >> 6;
  const int kr = (lane >> 4) * 8, rr = lane & 15;
  const int cr = (lane >> 4) * 4, cc = lane & 15;

  if (blockIdx.x < 64) {
    if (!do_l1) return;
    auto As = (__bf16 (*)[64])smem;                    // [64][64]  8KB
    auto Ws = (__bf16 (*)[64])(smem + 8192);           // [64][64]  8KB
    auto Gx = (float (*)[64][16])(smem + 16384);       // [4][64][16] 16KB
    const int n0 = blockIdx.x * 16;
    fx4 acc[4] = {};
    for (int k0 = 0; k0 < H1_; k0 += 64) {
      __syncthreads();
#pragma unroll
      for (int i = 0; i < 2; ++i) {
        int s = tid + i * 256;
        int r = s >> 3, c = (s & 7) * 8;
        *(bfx8*)&As[r][c] = *(const bfx8*)&h1p[(size_t)r * H1_ + k0 + c];
        int g = r >> 4, j = r & 15;
        *(bfx8*)&Ws[r][c] = *(const bfx8*)&whh1[(size_t)(g * H1_ + n0 + j) * H1_ + k0 + c];
      }
      __syncthreads();
#pragma unroll
      for (int kh = 0; kh < 2; ++kh) {
        bfx8 b = *(const bfx8*)&Ws[wave*16 + rr][kh*32 + kr];
#pragma unroll
        for (int mi = 0; mi < 4; ++mi) {
          bfx8 a = *(const bfx8*)&As[mi*16 + rr][kh*32 + kr];
          acc[mi] = mfma16(a, b, acc[mi]);
        }
      }
    }
#pragma unroll
    for (int mi = 0; mi < 4; ++mi)
#pragma unroll
      for (int r = 0; r < 4; ++r)
        Gx[wave][mi*16 + cr + r][cc] = acc[mi][r];
    __syncthreads();
#pragma unroll
    for (int j = 0; j < 4; ++j) {
      int idx = tid + j * 256;
      int b = idx >> 4, col = idx & 15;
      int gc = n0 + col;
      size_t grow = (size_t)(tc * 64 + b) * G1N;
      float gi = Gx[0][b][col] + G1c[grow + gc]        + bih1[gc]        + bhh1[gc];
      float gf = Gx[1][b][col] + G1c[grow + 1024 + gc] + bih1[1024 + gc] + bhh1[1024 + gc];
      float gg = Gx[2][b][col] + G1c[grow + 2048 + gc] + bih1[2048 + gc] + bhh1[2048 + gc];
      float go = Gx[3][b][col] + G1c[grow + 3072 + gc] + bih1[3072 + gc] + bhh1[3072 + gc];
      float cp = c1[b * H1_ + gc];
      float cn = sigmoidf_(gf) * cp + sigmoidf_(gi) * tanhf(gg);
      c1[b * H1_ + gc] = cn;
      h1n[b * H1_ + gc] = (__bf16)(sigmoidf_(go) * tanhf(cn));
    }
  } else {
    if (!do_l2) return;
    auto As = (__bf16 (*)[64])smem;                    // [64][64]  8KB
    auto Ws = (__bf16 (*)[64])(smem + 8192);           // [128][64] 16KB
    auto Gx = (float (*)[64][32])(smem + 8192 + 16384);// [4][64][32] 32KB
    const int n0 = (blockIdx.x - 64) * 32;
    fx4 acc[4][2] = {};
    for (int k0 = 0; k0 < F2_; k0 += 64) {
      __syncthreads();
#pragma unroll
      for (int i = 0; i < 2; ++i) {
        int s = tid + i * 256;
        int r = s >> 3, c = (s & 7) * 8;
        *(bfx8*)&As[r][c] = *(const bfx8*)&x2[(size_t)r * F2_ + k0 + c];
      }
#pragma unroll
      for (int i = 0; i < 4; ++i) {
        int s = tid + i * 256;
        int r = s >> 3, c = (s & 7) * 8;
        int g = r >> 5, j = r & 31;
        *(bfx8*)&Ws[r][c] = *(const bfx8*)&wih2[(size_t)(g * H2_ + n0 + j) * F2_ + k0 + c];
      }
      __syncthreads();
#pragma unroll
      for (int kh = 0; kh < 2; ++kh) {
        bfx8 b0 = *(const bfx8*)&Ws[wave*32 + rr][kh*32 + kr];
        bfx8 b1 = *(const bfx8*)&Ws[wave*32 + 16 + rr][kh*32 + kr];
#pragma unroll
        for (int mi = 0; mi < 4; ++mi) {
          bfx8 a = *(const bfx8*)&As[mi*16 + rr][kh*32 + kr];
          acc[mi][0] = mfma16(a, b0, acc[mi][0]);
          acc[mi][1] = mfma16(a, b1, acc[mi][1]);
        }
      }
    }
#pragma unroll
    for (int mi = 0; mi < 4; ++mi)
#pragma unroll
      for (int ni = 0; ni < 2; ++ni)
#pragma unroll
        for (int r = 0; r < 4; ++r)
          Gx[wave][mi*16 + cr + r][ni*16 + cc] = acc[mi][ni][r];
    __syncthreads();
#pragma unroll
    for (int j = 0; j < 8; ++j) {
      int idx = tid + j * 256;
      int b = idx >> 5, col = idx & 31;
      int hc = n0 + col;
      float gi = Gx[0][b][col] + g2p[b * G2N + hc];
      float gf = Gx[1][b][col] + g2p[b * G2N + 256 + hc];
      float gg = Gx[2][b][col] + g2p[b * G2N + 512 + hc];
      float go = Gx[3][b][col] + g2p[b * G2N + 768 + hc];
      float cp = c2[b * H2_ + hc];
      float cn = sigmoidf_(gf) * cp + sigmoidf_(gi) * tanhf(gg);
      c2[b * H2_ + hc] = cn;
      h2[b * H2_ + hc] = (__bf16)(sigmoidf_(go) * tanhf(cn));
    }
  }
}

// ---------------- S2 kernel: [0..7] fc2  [8..23] hh2-partial  [24] fc3 for t-1 ----------
__launch_bounds__(256)
__global__ void k_S2(const __bf16* __restrict__ h1, const __bf16* __restrict__ wfc2,
                     const float* __restrict__ bfc2, __bf16* __restrict__ x2,
                     const __bf16* __restrict__ h2, const __bf16* __restrict__ whh2,
                     const float* __restrict__ bih2, const float* __restrict__ bhh2,
                     float* __restrict__ g2p,
                     const __bf16* __restrict__ w3, const float* __restrict__ b3,
                     float* __restrict__ yprev, int do_fc3)
{
  __shared__ __bf16 As[64][64];
  __shared__ __bf16 Ws[64][64];
  const int lane = threadIdx.x & 63, wave = threadIdx.x >> 6;
  const int cr = (lane >> 4) * 4, cc = lane & 15;
  fx4 acc[4] = {};
  if (blockIdx.x < 8) {
    const int n0 = blockIdx.x * 64;
    gemm_bk64(h1, H1_, wfc2 + (size_t)n0 * H1_, H1_, H1_, As, Ws, acc);
    int col = n0 + wave*16 + cc;
    float bv = bfc2[col];
#pragma unroll
    for (int mi = 0; mi < 4; ++mi)
#pragma unroll
      for (int r = 0; r < 4; ++r)
        x2[(size_t)(mi*16 + cr + r) * F2_ + col] = (__bf16)leaky_tanh_(acc[mi][r] + bv);
  } else if (blockIdx.x < 24) {
    const int n0 = (blockIdx.x - 8) * 64;
    gemm_bk64(h2, H2_, whh2 + (size_t)n0 * H2_, H2_, H2_, As, Ws, acc);
    int col = n0 + wave*16 + cc;
    float bv = bih2[col] + bhh2[col];
#pragma unroll
    for (int mi = 0; mi < 4; ++mi)
#pragma unroll
      for (int r = 0; r < 4; ++r)
        g2p[(size_t)(mi*16 + cr + r) * G2N + col] = acc[mi][r] + bv;
  } else {
    if (!do_fc3) return;
    gemm_bk64(h2, H2_, w3, H2_, H2_, As, Ws, acc);
    int col = wave*16 + cc;
    float bv = b3[col];
#pragma unroll
    for (int mi = 0; mi < 4; ++mi)
#pragma unroll
      for (int r = 0; r < 4; ++r)
        yprev[(size_t)(mi*16 + cr + r) * O_ + col] = acc[mi][r] + bv;
  }
}

// ---------------- final-step fc3 ----------------
__launch_bounds__(256)
__global__ void k_fc3(const __bf16* __restrict__ h2, const __bf16* __restrict__ w3,
                      const float* __restrict__ b3, float* __restrict__ y)
{
  __shared__ __bf16 As[64][64];
  __shared__ __bf16 Ws[64][64];
  const int lane = threadIdx.x & 63, wave = threadIdx.x >> 6;
  const int cr = (lane >> 4) * 4, cc = lane & 15;
  fx4 acc[4] = {};
  gemm_bk64(h2, H2_, w3, H2_, H2_, As, Ws, acc);
  int col = wave*16 + cc;
  float bv = b3[col];
#pragma unroll
  for (int mi = 0; mi < 4; ++mi)
#pragma unroll
    for (int r = 0; r < 4; ++r)
      y[(size_t)(mi*16 + cr + r) * O_ + col] = acc[mi][r] + bv;
}

// ---------------- host launcher ----------------
extern "C" void kernel_launch(void* const* d_in, const int* in_sizes, int n_in,
                              void* d_out, int out_size, void* d_ws, size_t ws_size,
                              hipStream_t stream)
{
  (void)in_sizes; (void)n_in; (void)out_size;
  const float* f_in = (const float*)d_in[0];
  const float* fc1w = (const float*)d_in[1];
  const float* fc1b = (const float*)d_in[2];
  const float* wih1 = (const float*)d_in[3];
  const float* whh1 = (const float*)d_in[4];
  const float* bih1 = (const float*)d_in[5];
  const float* bhh1 = (const float*)d_in[6];
  const float* fc2w = (const float*)d_in[7];
  const float* fc2b = (const float*)d_in[8];
  const float* wih2 = (const float*)d_in[9];
  const float* whh2 = (const float*)d_in[10];
  const float* bih2 = (const float*)d_in[11];
  const float* bhh2 = (const float*)d_in[12];
  const float* fc3w = (const float*)d_in[13];
  const float* fc3b = (const float*)d_in[14];
  float* out = (float*)d_out;

  char* base = (char*)d_ws;
  size_t off = 0;
  auto alloc = [&](size_t bytes) -> char* {
    char* q = base + off;
    off = (off + bytes + 255) & ~(size_t)255;
    return q;
  };
  __bf16* wb_fc1 = (__bf16*)alloc((size_t)H_ * I_ * 2);
  __bf16* wb_ih1 = (__bf16*)alloc((size_t)G1N * H_ * 2);
  __bf16* wb_hh1 = (__bf16*)alloc((size_t)G1N * H1_ * 2);
  __bf16* wb_fc2 = (__bf16*)alloc((size_t)F2_ * H1_ * 2);
  __bf16* wb_ih2 = (__bf16*)alloc((size_t)G2N * F2_ * 2);
  __bf16* wb_hh2 = (__bf16*)alloc((size_t)G2N * H2_ * 2);
  __bf16* wb_fc3 = (__bf16*)alloc((size_t)O_ * H2_ * 2);
  __bf16* in_bf  = (__bf16*)alloc((size_t)T_ * B_ * I_ * 2);
  __bf16* h1b    = (__bf16*)alloc((size_t)2 * B_ * H1_ * 2);  // double-buffered h1
  float*  c1     = (float*) alloc((size_t)B_ * H1_ * 4);
  __bf16* h2b    = (__bf16*)alloc((size_t)B_ * H2_ * 2);
  float*  c2     = (float*) alloc((size_t)B_ * H2_ * 4);
  __bf16* x2     = (__bf16*)alloc((size_t)B_ * F2_ * 2);
  float*  g2p    = (float*) alloc((size_t)B_ * G2N * 4);
  size_t fixed = off;
  int Tc = 64;
  while (Tc > 2 && fixed + (size_t)Tc * 64 * ((size_t)H_ * 2 + (size_t)G1N * 4) + 4096 > ws_size)
    Tc >>= 1;
  __bf16* Xc  = (__bf16*)alloc((size_t)Tc * 64 * H_ * 2);
  float*  G1c = (float*) alloc((size_t)Tc * 64 * G1N * 4);

  // bf16 conversions (weights + inputs)
  struct CV { const float* s; __bf16* d; int n; } cvs[8] = {
    {fc1w, wb_fc1, H_ * I_},   {wih1, wb_ih1, G1N * H_},  {whh1, wb_hh1, G1N * H1_},
    {fc2w, wb_fc2, F2_ * H1_}, {wih2, wb_ih2, G2N * F2_}, {whh2, wb_hh2, G2N * H2_},
    {fc3w, wb_fc3, O_ * H2_},  {f_in, in_bf, T_ * B_ * I_},
  };
  for (int i = 0; i < 8; ++i) {
    int n4 = cvs[i].n / 4;
    int blocks = (n4 + 255) / 256;
    if (blocks > 2048) blocks = 2048;
    k_f2b<<<blocks, 256, 0, stream>>>(cvs[i].s, cvs[i].d, n4);
  }
  // zero recurrent state (h1b .. c2 are contiguous in the carve above)
  size_t zbytes = (size_t)((char*)c2 + (size_t)B_ * H2_ * 4 - (char*)h1b);
  hipMemsetAsync(h1b, 0, zbytes, stream);

  const int Mc = Tc * 64;
  const int chunks = T_ / Tc;
  for (int ch = 0; ch < chunks; ++ch) {
    // X1 = leaky_tanh(inputs @ fc1^T + b)  (bf16 out)
    k_gemm<<<dim3(H_ / 128, Mc / 128), 256, 0, stream>>>(
        in_bf + (size_t)ch * Mc * I_, wb_fc1, nullptr, Xc, fc1b, Mc, H_, I_, 1);
    // G1 = X1 @ w_ih1^T  (fp32 out)
    k_gemm<<<dim3(G1N / 128, Mc / 128), 256, 0, stream>>>(
        Xc, wb_ih1, G1c, nullptr, nullptr, Mc, G1N, H_, 0);
    for (int s = 0; s < Tc; ++s) {
      int t = ch * Tc + s;
      const __bf16* h1p = h1b + (size_t)(t & 1) * B_ * H1_;
      __bf16* h1n = h1b + (size_t)((t & 1) ^ 1) * B_ * H1_;
      k_F<<<72, 256, 0, stream>>>(1, (int)(t > 0), G1c, s, h1p, h1n, c1,
                                  wb_hh1, bih1, bhh1, x2, wb_ih2, g2p, c2, h2b);
      float* yprev = out + (size_t)(t > 0 ? t - 1 : 0) * B_ * O_;
      k_S2<<<25, 256, 0, stream>>>(h1n, wb_fc2, fc2b, x2, h2b, wb_hh2,
                                   bih2, bhh2, g2p, wb_fc3, fc3b, yprev, (int)(t > 0));
    }
  }
  // tail: LSTM2 for t=511, then fc3 for t=511
  k_F<<<72, 256, 0, stream>>>(0, 1, G1c, 0, h1b, h1b, c1,
                              wb_hh1, bih1, bhh1, x2, wb_ih2, g2p, c2, h2b);
  k_fc3<<<1, 256, 0, stream>>>(h2b, wb_fc3, fc3b, out + (size_t)(T_ - 1) * B_ * O_);
}